// Round 10
// baseline (544.183 us; speedup 1.0000x reference)
//
#include <hip/hip_runtime.h>
#include <math.h>

#define NBATCH 2
#define LQ     19560
#define LEN    19560
#define NQ     (NBATCH * LQ)      // 39120
#define DMODEL 256
#define NHEADS 8
#define HDIM   32
#define NLEV   4
#define NPTS   4
#define LDQS   384                // QS row stride fp32: [0..255]=offsets,
                                  // [256..383]=bf16 Qb (or aw in fallback mode)

typedef __bf16 bf16x8 __attribute__((ext_vector_type(8)));
typedef float  f32x4  __attribute__((ext_vector_type(4)));
typedef float  f32x2  __attribute__((ext_vector_type(2)));

__device__ inline unsigned short f2bf(float f) {
    unsigned int u = __float_as_uint(f);
    u += 0x7FFFu + ((u >> 16) & 1u);     // RNE
    return (unsigned short)(u >> 16);
}
// two bf16 packed in a dword -> two exact f32 (lo = u<<16, hi = u & 0xFFFF0000)
__device__ inline f32x2 bfpair(unsigned int u) {
    f32x2 r;
    r.x = __uint_as_float(u << 16);
    r.y = __uint_as_float(u & 0xFFFF0000u);
    return r;
}

// ---------------------------------------------------------------------------
// Merged preprocessing (one dispatch, disjoint outputs):
//   b in [0,19560):     fp32->bf16 convert. q0/q1 -> Qb embedded in QS aw bytes
//                       (row*768 + 512 shorts); f0/f1 -> Fb (linear, = Ocat).
//   b in [19560,20200): weight transpose/pack (Wvt, Wsoawt, bsoaw)
//   b in [20200,20456): fused tail weights Wfcat = (Wo@Wagg)^T bf16, bfused
// ---------------------------------------------------------------------------
__global__ __launch_bounds__(256) void prep_all(
    const float* __restrict__ q0, const float* __restrict__ q1,
    const float* __restrict__ f0, const float* __restrict__ f1,
    const float* __restrict__ Wv, const float* __restrict__ Wso,
    const float* __restrict__ Waw, const float* __restrict__ bso,
    const float* __restrict__ baw,
    const float* __restrict__ Wo, const float* __restrict__ Wagg,
    const float* __restrict__ bo, const float* __restrict__ bagg,
    unsigned short* __restrict__ Qb0, unsigned short* __restrict__ Qb1,
    unsigned short* __restrict__ Fb0, unsigned short* __restrict__ Fb1,
    unsigned short* __restrict__ Wvt, unsigned short* __restrict__ Wsoawt,
    float* __restrict__ bsoaw,
    unsigned short* __restrict__ Wfcat, float* __restrict__ bfused)
{
    const int b = blockIdx.x;
    if (b < 19560) {
        const int tsel = b / 4890;
        const int x = b - tsel * 4890;
        const float* s = (tsel & 2) ? ((tsel & 1) ? f1 : f0) : ((tsel & 1) ? q1 : q0);
        unsigned short* d = (tsel & 2) ? ((tsel & 1) ? Fb1 : Fb0) : ((tsel & 1) ? Qb1 : Qb0);
        size_t i = ((size_t)x * 256 + threadIdx.x) * 8;
        float4 a = *(const float4*)(s + i);
        float4 c = *(const float4*)(s + i + 4);
        union { uint4 u; unsigned short h[8]; } t;
        t.h[0] = f2bf(a.x); t.h[1] = f2bf(a.y); t.h[2] = f2bf(a.z); t.h[3] = f2bf(a.w);
        t.h[4] = f2bf(c.x); t.h[5] = f2bf(c.y); t.h[6] = f2bf(c.z); t.h[7] = f2bf(c.w);
        if (tsel & 2) {
            *(uint4*)(d + i) = t.u;                         // Fb linear
        } else {
            size_t row = i >> 8; int c8 = (int)(i & 255);   // Qb strided into QS rows
            *(uint4*)(d + row * 768 + 512 + c8) = t.u;
        }
    } else if (b < 19560 + 640) {
        int o = (b - 19560) * 256 + threadIdx.x;
        if (o < 65536) {
            int n = o >> 8, k = o & 255;
            Wvt[o] = f2bf(Wv[(size_t)k * 256 + n]);
        } else {
            int p = o - 65536;
            int n = p >> 8, k = p & 255;
            float v = (n < 256) ? Wso[(size_t)k * 256 + n] : Waw[(size_t)k * 128 + (n - 256)];
            Wsoawt[p] = f2bf(v);
        }
        if (o < 384) bsoaw[o] = (o < 256) ? bso[o] : baw[o - 256];
    } else {
        int k = b - 20200;
        int n = threadIdx.x;
        float s0 = 0.f, s1 = 0.f;
        for (int j = 0; j < 256; j++) {
            float w = Wo[k * 256 + j];
            s0 += w * Wagg[j * 256 + n];
            s1 += w * Wagg[(256 + j) * 256 + n];
        }
        Wfcat[(size_t)n * 512 + k]       = f2bf(s0);
        Wfcat[(size_t)n * 512 + 256 + k] = f2bf(s1);
        if (k == 0) {
            float bb = bagg[n];
            for (int j = 0; j < 256; j++)
                bb += bo[j] * (Wagg[j * 256 + n] + Wagg[(256 + j) * 256 + n]);
            bfused[n] = bb;
        }
    }
}

// ---------------------------------------------------------------------------
// Mega GEMM: uniform 128x128 K=256 blocks, z (+zbase) selects role:
//  z 0,1: offsets  A=Qa_z (lda 768), Bt rows 0..255,  out QS_z fp32 (ld 384)
//  z 2,3: values   A=Fb_z (lda 256), Bt=Wvt,          out V_z bf16 scatter
//  z 4:   logits BOTH iters (x=0 only): two K-passes (Qa0->acc, Qa1->acc2),
//         Bt rows 256..383, then IN-REGISTER joint softmax (16 cols of head
//         h=(wn*4+ni) live in lr 0..15 of a quad -> 4x shfl_xor over both
//         accs) -> writes NORMALIZED weights to AW0/AW1 (ld awld).
//  AW is disjoint from everything read in this dispatch -> no race.
//  Fallback (zbase=4 separate dispatch): AW aliases QS aw bytes (over Qb),
//  stream order + panel-local epilogue write keep it safe (R8-proven).
// ---------------------------------------------------------------------------
__global__ __launch_bounds__(256) void gemm_mega(
    const unsigned short* __restrict__ Qa0, const unsigned short* __restrict__ Qa1,
    const unsigned short* __restrict__ Fb0, const unsigned short* __restrict__ Fb1,
    const unsigned short* __restrict__ Wsoawt, const unsigned short* __restrict__ Wvt,
    const float* __restrict__ bsoaw, const float* __restrict__ bv,
    float* __restrict__ QS0, float* __restrict__ QS1,
    unsigned short* __restrict__ V0, unsigned short* __restrict__ V1,
    float* __restrict__ AW0, float* __restrict__ AW1, int awld, int zbase)
{
    const int z = blockIdx.z + zbase;
    const int isVal = (z == 2 || z == 3);
    const int isLog = (z == 4);
    if (isLog && blockIdx.x != 0) return;
    const int zz = z & 1;

    __shared__ __align__(16) unsigned short As[128 * 64];
    __shared__ __align__(16) unsigned short Bs[128 * 64];

    const unsigned short* A0p = isVal ? (zz ? Fb1 : Fb0)
                              : (isLog ? Qa0 : (zz ? Qa1 : Qa0));
    const unsigned short* Bt = isVal ? Wvt : Wsoawt;
    const int lda = isVal ? 256 : 768;
    const int btrow0 = isLog ? 256 : 0;

    const int tid  = threadIdx.x;
    const int w    = tid >> 6, lane = tid & 63;
    const int wm = w >> 1, wn = w & 1;
    const int m0 = blockIdx.y * 128, n0 = blockIdx.x * 128;
    const int lr = lane & 15, quad = lane >> 4;

    const int sr  = lane >> 3;
    const int scl = (lane & 7) ^ sr;
    const int colb = scl * 8;
    size_t arow[4], brow[4];
    #pragma unroll
    for (int j = 0; j < 4; j++) {
        int r = (w * 4 + j) * 8 + sr;
        int ra = m0 + r; if (ra > NQ - 1) ra = NQ - 1;
        arow[j] = (size_t)ra * lda;
        brow[j] = (size_t)(btrow0 + n0 + r) * 256;
    }

    const f32x4 zero = {0.f, 0.f, 0.f, 0.f};
    f32x4 acc[4][4], acc2[4][4];
    #pragma unroll
    for (int i = 0; i < 4; i++)
        #pragma unroll
        for (int j = 0; j < 4; j++) { acc[i][j] = zero; acc2[i][j] = zero; }

    auto kloop = [&](const unsigned short* A, f32x4 (&ac)[4][4]) {
        for (int t = 0; t < 256; t += 64) {
            #pragma unroll
            for (int j = 0; j < 4; j++) {
                int lofs = __builtin_amdgcn_readfirstlane((w * 4 + j) * 1024);
                __builtin_amdgcn_global_load_lds(
                    (const __attribute__((address_space(1))) void*)(A + arow[j] + t + colb),
                    (__attribute__((address_space(3))) void*)((char*)As + lofs), 16, 0, 0);
                __builtin_amdgcn_global_load_lds(
                    (const __attribute__((address_space(1))) void*)(Bt + brow[j] + t + colb),
                    (__attribute__((address_space(3))) void*)((char*)Bs + lofs), 16, 0, 0);
            }
            __syncthreads();
            #pragma unroll
            for (int kk = 0; kk < 2; kk++) {
                bf16x8 af[4], bff[4];
                #pragma unroll
                for (int mi = 0; mi < 4; mi++) {
                    int R = wm * 64 + mi * 16 + lr;
                    int pc = ((kk * 4 + quad) ^ (lr & 7)) * 16;
                    af[mi] = *(const bf16x8*)((const char*)As + R * 128 + pc);
                }
                #pragma unroll
                for (int ni = 0; ni < 4; ni++) {
                    int R = wn * 64 + ni * 16 + lr;
                    int pc = ((kk * 4 + quad) ^ (lr & 7)) * 16;
                    bff[ni] = *(const bf16x8*)((const char*)Bs + R * 128 + pc);
                }
                #pragma unroll
                for (int mi = 0; mi < 4; mi++)
                    #pragma unroll
                    for (int ni = 0; ni < 4; ni++)
                        ac[mi][ni] = __builtin_amdgcn_mfma_f32_16x16x32_bf16(
                            af[mi], bff[ni], ac[mi][ni], 0, 0, 0);
            }
            __syncthreads();
        }
    };

    kloop(A0p, acc);
    if (isLog) kloop(Qa1, acc2);

    if (isLog) {
        // in-register joint softmax over {acc (iter0), acc2 (iter1)}, store
        float bvv[4];
        #pragma unroll
        for (int ni = 0; ni < 4; ni++) bvv[ni] = bsoaw[256 + wn * 64 + ni * 16 + lr];
        #pragma unroll
        for (int mi = 0; mi < 4; mi++) {
            #pragma unroll
            for (int reg = 0; reg < 4; reg++) {
                int row = m0 + wm * 64 + mi * 16 + quad * 4 + reg;
                #pragma unroll
                for (int ni = 0; ni < 4; ni++) {
                    float a = acc[mi][ni][reg] + bvv[ni];
                    float c = acc2[mi][ni][reg] + bvv[ni];
                    float m = fmaxf(a, c);
                    #pragma unroll
                    for (int d = 1; d < 16; d <<= 1) m = fmaxf(m, __shfl_xor(m, d));
                    float ea = expf(a - m), ec = expf(c - m);
                    float s = ea + ec;
                    #pragma unroll
                    for (int d = 1; d < 16; d <<= 1) s += __shfl_xor(s, d);
                    float inv = 1.0f / s;
                    if (row < NQ) {
                        int col = wn * 64 + ni * 16 + lr;   // 0..127
                        AW0[(size_t)row * awld + col] = ea * inv;
                        AW1[(size_t)row * awld + col] = ec * inv;
                    }
                }
            }
        }
        return;
    }

    float* Cf = zz ? QS1 : QS0;
    unsigned short* Cb = zz ? V1 : V0;
    #pragma unroll
    for (int mi = 0; mi < 4; mi++) {
        #pragma unroll
        for (int reg = 0; reg < 4; reg++) {
            int row = m0 + wm * 64 + mi * 16 + quad * 4 + reg;
            if (row >= NQ) continue;
            #pragma unroll
            for (int ni = 0; ni < 4; ni++) {
                int col = n0 + wn * 64 + ni * 16 + lr;
                if (!isVal) {
                    Cf[(size_t)row * LDQS + col] = acc[mi][ni][reg] + bsoaw[col];
                } else {
                    float v = acc[mi][ni][reg] + bv[col];
                    int n = row >= LQ ? 1 : 0;
                    int pos = row - n * LQ;
                    int h = col >> 5, d = col & 31;
                    Cb[((size_t)(n * NHEADS + h) * LEN + pos) * HDIM + d] = f2bf(v);
                }
            }
        }
    }
}

// ---------------------------------------------------------------------------
// Merged deformable sampling (both iters), v8 = R8's verified 129.5us
// structure (u16 Sidx, padded [16][65][4] planes, no softmax, 52-VGPR path),
// with aw read from the NORMALIZED AW buffer (one float4 per lane, own iter).
//  Phase 1: lane lj owns level lj: 4 points -> idx(u16)+wt(f32) in LDS.
//  Phase 2: 16-point gather, 4 lanes/query, lane owns 8 dims, dwordx4/corner.
// ---------------------------------------------------------------------------
#define QCHUNK 64
#define CHUNKS ((LQ + QCHUNK - 1) / QCHUNK)   // 306

__global__ __launch_bounds__(256) void ms_sample(
    const unsigned short* __restrict__ V0, const unsigned short* __restrict__ V1,
    const float* __restrict__ QS0, const float* __restrict__ QS1,
    const float* __restrict__ AW0, const float* __restrict__ AW1, int awld,
    const float* __restrict__ refp, unsigned short* __restrict__ Ocat)
{
    __shared__ unsigned short Sidx[16][65][4];  // [plane][ql][corner] u16 row idx
    __shared__ float          Swt [16][65][4];  // [plane][ql][corner] weight

    const int b = blockIdx.x;
    const int h = b & 7;
    const int rest = b >> 3;               // (it*2+n)*CHUNKS + chunk
    const int chunk = rest % CHUNKS;
    const int inn   = rest / CHUNKS;       // it*2 + n
    const int n  = inn & 1;
    const int it = inn >> 1;

    const int tid = threadIdx.x;
    const int ql  = tid >> 2;              // 0..63 query slot
    const int lj  = tid & 3;
    const int qraw = chunk * QCHUNK + ql;
    const bool valid = qraw < LQ;
    const int q  = valid ? qraw : LQ - 1;
    const int nq = n * LQ + q;

    const unsigned short* __restrict__ val = it ? V1 : V0;
    const float* __restrict__ QS = it ? QS1 : QS0;
    const float* __restrict__ AW = it ? AW1 : AW0;
    const unsigned short* __restrict__ vb2 =
        val + (size_t)(n * NHEADS + h) * LEN * HDIM;

    const int Hs[4] = {92, 46, 23, 12};
    const int Ws[4] = {160, 80, 40, 20};
    const int Ss[4] = {0, 14720, 18400, 19320};

    const float* prow = QS + (size_t)nq * LDQS;

    // ---- phase 1: this lane's level only (4 points) ----
    {
        const int H = Hs[lj], W = Ws[lj], S = Ss[lj];
        const float4 o0 = *(const float4*)(prow + (h << 5) + lj * 8);
        const float4 o1 = *(const float4*)(prow + (h << 5) + lj * 8 + 4);
        const float4 a4 = *(const float4*)(AW + (size_t)nq * awld + (h << 4) + lj * 4);
        const float2 rp = *(const float2*)(refp + (size_t)nq * 8 + lj * 2);
        const float fx = rp.x * (float)W - 0.5f;
        const float fy = rp.y * (float)H - 0.5f;
        const float oxs[4] = {o0.x, o0.z, o1.x, o1.z};
        const float oys[4] = {o0.y, o0.w, o1.y, o1.w};
        const float avs[4] = {a4.x, a4.y, a4.z, a4.w};
        #pragma unroll
        for (int k = 0; k < NPTS; k++) {
            const float x = fx + oxs[k];
            const float y = fy + oys[k];
            const float x0f = floorf(x), y0f = floorf(y);
            const int x0 = (int)x0f, y0 = (int)y0f;
            const float wx1 = x - x0f, wy1 = y - y0f;
            const float wx0 = 1.0f - wx1, wy0 = 1.0f - wy1;
            const int xc0 = min(max(x0, 0), W - 1);
            const int xc1 = min(max(x0 + 1, 0), W - 1);
            const int yc0 = min(max(y0, 0), H - 1);
            const int yc1 = min(max(y0 + 1, 0), H - 1);
            const float a = avs[k];
            const float ay0 = ((unsigned int)y0 < (unsigned int)H) ? a * wy0 : 0.f;
            const float ay1 = ((unsigned int)(y0 + 1) < (unsigned int)H) ? a * wy1 : 0.f;
            const float mx0 = ((unsigned int)x0 < (unsigned int)W) ? wx0 : 0.f;
            const float mx1 = ((unsigned int)(x0 + 1) < (unsigned int)W) ? wx1 : 0.f;
            const int r0 = S + yc0 * W, r1 = S + yc1 * W;
            union { uint2 u; unsigned short s4[4]; } ip;
            ip.s4[0] = (unsigned short)(r0 + xc0);
            ip.s4[1] = (unsigned short)(r0 + xc1);
            ip.s4[2] = (unsigned short)(r1 + xc0);
            ip.s4[3] = (unsigned short)(r1 + xc1);
            *(uint2*)&Sidx[lj * 4 + k][ql][0] = ip.u;
            float4 w4 = make_float4(ay0 * mx0, ay0 * mx1, ay1 * mx0, ay1 * mx1);
            *(float4*)&Swt[lj * 4 + k][ql][0] = w4;
        }
    }
    __syncthreads();

    // ---- phase 2: gather all 16 staged points ----
    const int dl = lj << 3;                // dim quarter 0,8,16,24
    const unsigned short* __restrict__ vdl = vb2 + dl;

    f32x2 acc[4];
    #pragma unroll
    for (int i = 0; i < 4; i++) acc[i] = (f32x2){0.f, 0.f};

    auto corner = [&](unsigned int eo, float wgt) {
        const uint4 c = *(const uint4*)(vdl + eo);
        const f32x2 w2 = {wgt, wgt};
        acc[0] += w2 * bfpair(c.x);
        acc[1] += w2 * bfpair(c.y);
        acc[2] += w2 * bfpair(c.z);
        acc[3] += w2 * bfpair(c.w);
    };

    #pragma unroll
    for (int p = 0; p < 16; p++) {
        const uint2 i2 = *(const uint2*)&Sidx[p][ql][0];
        const float4 w4 = *(const float4*)&Swt[p][ql][0];
        corner((i2.x & 0xFFFFu) << 5, w4.x);
        corner((i2.x >> 16) << 5, w4.y);
        corner((i2.y & 0xFFFFu) << 5, w4.z);
        corner((i2.y >> 16) << 5, w4.w);
    }

    if (valid) {
        union { uint4 u; unsigned short s[8]; } t;
        #pragma unroll
        for (int i = 0; i < 4; i++) {
            t.s[2 * i]     = f2bf(acc[i].x);
            t.s[2 * i + 1] = f2bf(acc[i].y);
        }
        *(uint4*)&Ocat[(size_t)nq * 512 + it * 256 + h * HDIM + dl] = t.u;
    }
}

// ---------------------------------------------------------------------------
// Tail GEMM: C = Ocat @ Wfcat^T + bfused, fp32 out. K=512.
// ---------------------------------------------------------------------------
__global__ __launch_bounds__(256) void gemm_tail(
    const unsigned short* __restrict__ A, const unsigned short* __restrict__ Bt,
    const float* __restrict__ bias, float* __restrict__ C)
{
    __shared__ __align__(16) unsigned short As[128 * 64];
    __shared__ __align__(16) unsigned short Bs[128 * 64];

    const int tid  = threadIdx.x;
    const int w    = tid >> 6, lane = tid & 63;
    const int wm = w >> 1, wn = w & 1;
    const int m0 = blockIdx.y * 128, n0 = blockIdx.x * 128;
    const int lr = lane & 15, quad = lane >> 4;

    const int sr  = lane >> 3;
    const int scl = (lane & 7) ^ sr;
    const int colb = scl * 8;
    size_t arow[4], brow[4];
    #pragma unroll
    for (int j = 0; j < 4; j++) {
        int r = (w * 4 + j) * 8 + sr;
        int ra = m0 + r; if (ra > NQ - 1) ra = NQ - 1;
        arow[j] = (size_t)ra * 512;
        brow[j] = (size_t)(n0 + r) * 512;
    }

    const f32x4 zero = {0.f, 0.f, 0.f, 0.f};
    f32x4 acc[4][4];
    #pragma unroll
    for (int i = 0; i < 4; i++)
        #pragma unroll
        for (int j = 0; j < 4; j++) acc[i][j] = zero;

    for (int t = 0; t < 512; t += 64) {
        #pragma unroll
        for (int j = 0; j < 4; j++) {
            int lofs = __builtin_amdgcn_readfirstlane((w * 4 + j) * 1024);
            __builtin_amdgcn_global_load_lds(
                (const __attribute__((address_space(1))) void*)(A + arow[j] + t + colb),
                (__attribute__((address_space(3))) void*)((char*)As + lofs), 16, 0, 0);
            __builtin_amdgcn_global_load_lds(
                (const __attribute__((address_space(1))) void*)(Bt + brow[j] + t + colb),
                (__attribute__((address_space(3))) void*)((char*)Bs + lofs), 16, 0, 0);
        }
        __syncthreads();

        #pragma unroll
        for (int kk = 0; kk < 2; kk++) {
            bf16x8 af[4], bff[4];
            #pragma unroll
            for (int mi = 0; mi < 4; mi++) {
                int R = wm * 64 + mi * 16 + lr;
                int pc = ((kk * 4 + quad) ^ (lr & 7)) * 16;
                af[mi] = *(const bf16x8*)((const char*)As + R * 128 + pc);
            }
            #pragma unroll
            for (int ni = 0; ni < 4; ni++) {
                int R = wn * 64 + ni * 16 + lr;
                int pc = ((kk * 4 + quad) ^ (lr & 7)) * 16;
                bff[ni] = *(const bf16x8*)((const char*)Bs + R * 128 + pc);
            }
            #pragma unroll
            for (int mi = 0; mi < 4; mi++)
                #pragma unroll
                for (int ni = 0; ni < 4; ni++)
                    acc[mi][ni] = __builtin_amdgcn_mfma_f32_16x16x32_bf16(
                        af[mi], bff[ni], acc[mi][ni], 0, 0, 0);
        }
        __syncthreads();
    }

    #pragma unroll
    for (int mi = 0; mi < 4; mi++) {
        #pragma unroll
        for (int reg = 0; reg < 4; reg++) {
            int row = m0 + wm * 64 + mi * 16 + quad * 4 + reg;
            if (row >= NQ) continue;
            #pragma unroll
            for (int ni = 0; ni < 4; ni++) {
                int col = n0 + wn * 64 + ni * 16 + lr;
                C[(size_t)row * 256 + col] = acc[mi][ni][reg] + bias[col];
            }
        }
    }
}

// ---------------------------------------------------------------------------
extern "C" void kernel_launch(void* const* d_in, const int* in_sizes, int n_in,
                              void* d_out, int out_size, void* d_ws, size_t ws_size,
                              hipStream_t stream)
{
    const float* q0    = (const float*)d_in[0];
    const float* q1    = (const float*)d_in[1];
    const float* refp  = (const float*)d_in[2];
    const float* f0    = (const float*)d_in[3];
    const float* f1    = (const float*)d_in[4];
    const float* W_so  = (const float*)d_in[7];
    const float* b_so  = (const float*)d_in[8];
    const float* W_aw  = (const float*)d_in[9];
    const float* b_aw  = (const float*)d_in[10];
    const float* W_v   = (const float*)d_in[11];
    const float* b_v   = (const float*)d_in[12];
    const float* W_o   = (const float*)d_in[13];
    const float* b_o   = (const float*)d_in[14];
    const float* W_agg = (const float*)d_in[15];
    const float* b_agg = (const float*)d_in[16];
    float* out = (float*)d_out;

    float* ws = (float*)d_ws;
    float* QS0 = ws;                                        // NQ*384 fp32
    float* QS1 = QS0 + (size_t)NQ * LDQS;                   // NQ*384 fp32
    unsigned short* V0   = (unsigned short*)(QS1 + (size_t)NQ * LDQS);  // NQ*256 bf16
    unsigned short* V1   = V0 + (size_t)NQ * 256;
    unsigned short* Ocat = V1 + (size_t)NQ * 256;           // NQ*512 bf16
    unsigned short* Wvt    = Ocat + (size_t)NQ * 512;       // 65536
    unsigned short* Wsoawt = Wvt + 65536;                   // 98304
    unsigned short* Wfcat  = Wsoawt + 98304;                // 131072
    float* bsoaw = (float*)(Wfcat + 131072);                // 384
    float* bfus  = bsoaw + 384;                             // 256
    float* wsend = bfus + 256;

    // Qb embedded in QS aw bytes (row*768+512 shorts). Fb aliases Ocat (dead
    // after mega reads it; ms_sample then overwrites Ocat).
    unsigned short* Qb0 = (unsigned short*)QS0;
    unsigned short* Qb1 = (unsigned short*)QS1;
    unsigned short* Fb0 = Ocat;
    unsigned short* Fb1 = Ocat + (size_t)NQ * 256;
    const unsigned short* Qa0 = (const unsigned short*)QS0 + 512;  // A base, lda=768
    const unsigned short* Qa1 = (const unsigned short*)QS1 + 512;

    // Normalized-aw buffer: separate AW region when workspace allows (merged:
    // z=4 inside mega — AW disjoint from Qb, no race). Fallback: z=4 as a
    // separate dispatch AFTER mega, AW aliasing QS aw bytes (stream order +
    // panel-local epilogue keep Qb reads safe).
    size_t aw_bytes = (size_t)NQ * 128 * 4 * 2;
    size_t need_merged = ((size_t)((char*)wsend - (char*)ws)) + aw_bytes;
    const int merged = ws_size >= need_merged;
    float *AW0, *AW1;
    int awld;
    if (merged) {
        AW0 = wsend;
        AW1 = AW0 + (size_t)NQ * 128;
        awld = 128;
    } else {
        AW0 = QS0 + 256;
        AW1 = QS1 + 256;
        awld = LDQS;
    }

    const int MB = (NQ + 127) / 128;   // 306
    dim3 blk(256);

    // 1) merged preprocessing: converts + weight prep + fused tail weights
    prep_all<<<20456, blk, 0, stream>>>(
        q0, q1, f0, f1, W_v, W_so, W_aw, b_so, b_aw, W_o, W_agg, b_o, b_agg,
        Qb0, Qb1, Fb0, Fb1, Wvt, Wsoawt, bsoaw, Wfcat, bfus);

    // 2) mega GEMM: offsets + values (+ both-iter logits w/ softmax when merged)
    if (merged) {
        gemm_mega<<<dim3(2, MB, 5), blk, 0, stream>>>(
            Qa0, Qa1, Fb0, Fb1, Wsoawt, Wvt, bsoaw, b_v,
            QS0, QS1, V0, V1, AW0, AW1, awld, 0);
    } else {
        gemm_mega<<<dim3(2, MB, 4), blk, 0, stream>>>(
            Qa0, Qa1, Fb0, Fb1, Wsoawt, Wvt, bsoaw, b_v,
            QS0, QS1, V0, V1, AW0, AW1, awld, 0);
        gemm_mega<<<dim3(1, MB, 1), blk, 0, stream>>>(
            Qa0, Qa1, Fb0, Fb1, Wsoawt, Wvt, bsoaw, b_v,
            QS0, QS1, V0, V1, AW0, AW1, awld, 4);
    }

    // 3) merged sampler (both iters) -> Ocat
    ms_sample<<<2 * 2 * CHUNKS * 8, blk, 0, stream>>>(
        V0, V1, QS0, QS1, AW0, AW1, awld, refp, Ocat);

    // 4) single K=512 tail GEMM -> out
    gemm_tail<<<dim3(2, MB, 1), blk, 0, stream>>>(Ocat, Wfcat, bfus, out);
}